// Round 2
// baseline (101.052 us; speedup 1.0000x reference)
//
#include <hip/hip_runtime.h>
#include <math.h>

#define NB 8192
#define NF 512
#define NP 64
#define NC 100
#define EPSF 1e-4f
#define LOG2E 1.44269504088896340736f

// ---- workspace layout (bytes) ----
// dpre: [4][NB][NP] f32 partial dots (K-split 4)     = 8 MiB
// xsqp: [4][NB]     f32 partial ||x||^2              = 128 KiB
// upad: [NP][128]   f32 u (cols 100..127 zero)       = 32 KiB
// wsq/kgam/alph: [NP] f32 each
#define DPRE_OFF   0ull
#define DPRE_SZ    (4ull*NB*NP*4ull)
#define XSQP_OFF   (DPRE_OFF + DPRE_SZ)
#define XSQP_SZ    (4ull*NB*4ull)
#define UPAD_OFF   (XSQP_OFF + XSQP_SZ)
#define UPAD_SZ    (NP*128ull*4ull)
#define WSQ_OFF    (UPAD_OFF + UPAD_SZ)
#define KGAM_OFF   (WSQ_OFF + 256ull)
#define ALPH_OFF   (KGAM_OFF + 256ull)

// K1: 512 GEMM blocks (tile 64 rows x 64 p x 128 k, K-split via blockIdx&3)
//     + 1 prep block (blockIdx==512) computing wsq, kgamma, alpha, u.
// NOTE: no float atomics anywhere — graph-replay tripwire requires bitwise-
// deterministic output, so ||x||^2 uses a fixed-order two-stage reduction.
__global__ __launch_bounds__(256)
void ds_k1(const float* __restrict__ x, const float* __restrict__ w,
           const float* __restrict__ xi, const float* __restrict__ eta,
           const float* __restrict__ beta,
           float* __restrict__ dpre, float* __restrict__ xsqp,
           float* __restrict__ upad, float* __restrict__ wsq,
           float* __restrict__ kgam, float* __restrict__ alph)
{
  const int blk = blockIdx.x;
  const int t   = threadIdx.x;

  if (blk == 512) {           // ---- prep block (tiny, hidden under GEMM) ----
    if (t < NP) {
      const int p = t;
      float s2 = 0.f;
      for (int k = 0; k < NF; k += 4) {
        float4 v = *(const float4*)&w[(size_t)p*NF + k];
        s2 += v.x*v.x + v.y*v.y + v.z*v.z + v.w*v.w;
      }
      wsq[p] = s2;
      float e = eta[p];
      kgam[p] = -LOG2E * e * e;            // exp(-g*d) = exp2(kgam*d)
      alph[p] = 1.f / (1.f + __expf(-xi[p]));
      float bs = 0.f;
      for (int c = 0; c < NC; ++c) { float b = beta[p*NC + c]; bs += b*b; }
      float inv = 1.f / bs;
      for (int c = 0; c < NC; ++c) { float b = beta[p*NC + c]; upad[p*128 + c] = b*b*inv; }
      for (int c = NC; c < 128; ++c) upad[p*128 + c] = 0.f;
    }
    return;
  }

  // ---- GEMM partial: rows [R0,R0+64) x all 64 p x k in [kbase,kbase+128) ----
  __shared__ __align__(16) float xt[64][36];  // pad 36: aligned b128 writes, ~2-way banks
  __shared__ float wt[64][33];                // pad 33: b32 reads conflict-free
  __shared__ float sqp[64][17];               // per-(row,quarter) |x|^2 partials
  const int s     = blk & 3;
  const int R0    = (blk >> 2) * 64;
  const int kbase = s * 128;
  const int r0 = (t >> 4) * 4;
  const int p0 = (t & 15) * 4;
  float acc[4][4] = {{0.f}};
  float xacc = 0.f;                           // row-t ||x||^2 (threads t<64)

  for (int cch = 0; cch < 2; ++cch) {
    const int kc = kbase + 64 * cch;
    __syncthreads();
    #pragma unroll
    for (int u = 0; u < 4; ++u) {
      const int idx = t + 256 * u;
      const int row = idx >> 4;
      const int kf  = (idx & 15) * 4;
      float4 v = *(const float4*)&x[(size_t)(R0 + row) * NF + kc + kf];
      sqp[row][idx & 15] = v.x*v.x + v.y*v.y + v.z*v.z + v.w*v.w;
      *(float4*)&xt[row][kf] = v;
      float4 wv = *(const float4*)&w[(size_t)row * NF + kc + kf];
      wt[row][kf]   = wv.x; wt[row][kf+1] = wv.y;
      wt[row][kf+2] = wv.z; wt[row][kf+3] = wv.w;
    }
    __syncthreads();
    if (t < 64) {                             // fixed-order, deterministic
      #pragma unroll
      for (int q = 0; q < 16; ++q) xacc += sqp[t][q];
    }
    #pragma unroll 8
    for (int kk = 0; kk < 64; ++kk) {
      float a0 = xt[r0+0][kk], a1 = xt[r0+1][kk], a2 = xt[r0+2][kk], a3 = xt[r0+3][kk];
      float b0 = wt[p0+0][kk], b1 = wt[p0+1][kk], b2 = wt[p0+2][kk], b3 = wt[p0+3][kk];
      acc[0][0] = fmaf(a0,b0,acc[0][0]); acc[0][1] = fmaf(a0,b1,acc[0][1]);
      acc[0][2] = fmaf(a0,b2,acc[0][2]); acc[0][3] = fmaf(a0,b3,acc[0][3]);
      acc[1][0] = fmaf(a1,b0,acc[1][0]); acc[1][1] = fmaf(a1,b1,acc[1][1]);
      acc[1][2] = fmaf(a1,b2,acc[1][2]); acc[1][3] = fmaf(a1,b3,acc[1][3]);
      acc[2][0] = fmaf(a2,b0,acc[2][0]); acc[2][1] = fmaf(a2,b1,acc[2][1]);
      acc[2][2] = fmaf(a2,b2,acc[2][2]); acc[2][3] = fmaf(a2,b3,acc[2][3]);
      acc[3][0] = fmaf(a3,b0,acc[3][0]); acc[3][1] = fmaf(a3,b1,acc[3][1]);
      acc[3][2] = fmaf(a3,b2,acc[3][2]); acc[3][3] = fmaf(a3,b3,acc[3][3]);
    }
  }
  #pragma unroll
  for (int i = 0; i < 4; ++i) {
    float4 st = make_float4(acc[i][0], acc[i][1], acc[i][2], acc[i][3]);
    *(float4*)&dpre[((size_t)s * NB + R0 + r0 + i) * NP + p0] = st;
  }
  if (t < 64) xsqp[(size_t)s * NB + R0 + t] = xacc;
}

// K2: per block 8 rows; half-wave (32 lanes) per row, 4 contiguous classes/lane.
// Preamble computes si (sum K-split partials, exp2, rowmax-normalize) into LDS,
// then 63 sequential Dempster steps with factored form
//   c = (m1+om1)*(m2+om2) - om1*om2   (gives 3*om1*om2 at the omega slot)
// normalizing every 4 steps (pure scale -> cancelled by final normalize).
__global__ __launch_bounds__(256)
void ds_k2(const float* __restrict__ dpre, const float* __restrict__ xsqp,
           const float* __restrict__ upad, const float* __restrict__ wsq,
           const float* __restrict__ kgam, const float* __restrict__ alph,
           float* __restrict__ out)
{
  __shared__ __align__(16) float u_lds[NP * 128];
  __shared__ float si_lds[8][64];
  const int t = threadIdx.x;

  #pragma unroll
  for (int uu = 0; uu < 8; ++uu) {
    const int idx = (t + 256 * uu) * 4;
    *(float4*)&u_lds[idx] = *(const float4*)&upad[idx];
  }

  const int r    = t >> 5;          // local row 0..7 (half-wave per row)
  const int lane = t & 31;
  const int grow = blockIdx.x * 8 + r;
  const int p2   = lane * 2;

  float dot0 = 0.f, dot1 = 0.f, xs = 0.f;
  #pragma unroll
  for (int s = 0; s < 4; ++s) {
    float2 v = *(const float2*)&dpre[((size_t)s * NB + grow) * NP + p2];
    dot0 += v.x; dot1 += v.y;
    xs   += xsqp[(size_t)s * NB + grow];
  }
  float d0  = xs + wsq[p2]   - 2.f * dot0;
  float d1  = xs + wsq[p2+1] - 2.f * dot1;
  float si0 = alph[p2]   * exp2f(kgam[p2]   * d0);
  float si1 = alph[p2+1] * exp2f(kgam[p2+1] * d1);
  float mx  = fmaxf(si0, si1);
  #pragma unroll
  for (int msk = 1; msk < 32; msk <<= 1) mx = fmaxf(mx, __shfl_xor(mx, msk, 64));
  float rinv = 1.f / (mx + EPSF);
  *(float2*)&si_lds[r][p2] = make_float2(si0 * rinv, si1 * rinv);
  __syncthreads();

  const bool isom = (lane == 25);   // class 100 (omega) lives at lane 25, slot 0
  float4 u0 = *(const float4*)&u_lds[lane * 4];
  float sp  = si_lds[r][0];
  float m0 = sp * u0.x, m1 = sp * u0.y, m2 = sp * u0.z, m3 = sp * u0.w;
  float om1 = 1.f - sp;
  if (isom) m0 = om1;

  for (int p = 1; p < NP; ++p) {
    sp = si_lds[r][p];
    float4 u = *(const float4*)&u_lds[p * 128 + lane * 4];
    float om2 = 1.f - sp;
    float nom = -(om1 * om2);
    float t20 = fmaf(sp, u.x, om2);
    t20 = isom ? (om2 + om2) : t20;        // omega slot: m2+om2 = 2*om2
    float t21 = fmaf(sp, u.y, om2);
    float t22 = fmaf(sp, u.z, om2);
    float t23 = fmaf(sp, u.w, om2);
    m0 = fmaf(m0 + om1, t20, nom);
    m1 = fmaf(m1 + om1, t21, nom);
    m2 = fmaf(m2 + om1, t22, nom);
    m3 = fmaf(m3 + om1, t23, nom);
    om1 = fmaf(nom, -2.f, -nom);           // 3*om1*om2
    if (isom) m0 = om1;                    // keep omega slot exactly consistent
    if ((p & 3) == 0) {                    // range-control renorm (pure scale)
      float ss = (m0 + m1) + (m2 + m3);
      #pragma unroll
      for (int msk = 1; msk < 32; msk <<= 1) ss += __shfl_xor(ss, msk, 64);
      float rn = __builtin_amdgcn_rcpf(ss);
      m0 *= rn; m1 *= rn; m2 *= rn; m3 *= rn; om1 *= rn;
    }
  }

  float ss = (m0 + m1) + (m2 + m3);
  #pragma unroll
  for (int msk = 1; msk < 32; msk <<= 1) ss += __shfl_xor(ss, msk, 64);
  float rn = 1.f / ss;                     // final normalize (reference: no EPS)
  m0 *= rn; m1 *= rn; m2 *= rn; m3 *= rn;

  float* orow = &out[(size_t)grow * 101];
  if (lane < 25) {
    orow[lane*4+0] = m0; orow[lane*4+1] = m1;
    orow[lane*4+2] = m2; orow[lane*4+3] = m3;
  } else if (lane == 25) {
    orow[100] = m0;
  }
}

extern "C" void kernel_launch(void* const* d_in, const int* in_sizes, int n_in,
                              void* d_out, int out_size, void* d_ws, size_t ws_size,
                              hipStream_t stream)
{
  const float* x    = (const float*)d_in[0];
  const float* w    = (const float*)d_in[1];
  const float* xi   = (const float*)d_in[2];
  const float* eta  = (const float*)d_in[3];
  const float* beta = (const float*)d_in[4];
  char* ws = (char*)d_ws;
  float* dpre = (float*)(ws + DPRE_OFF);
  float* xsqp = (float*)(ws + XSQP_OFF);
  float* upad = (float*)(ws + UPAD_OFF);
  float* wsqp = (float*)(ws + WSQ_OFF);
  float* kgam = (float*)(ws + KGAM_OFF);
  float* alph = (float*)(ws + ALPH_OFF);

  hipLaunchKernelGGL(ds_k1, dim3(513), dim3(256), 0, stream,
                     x, w, xi, eta, beta, dpre, xsqp, upad, wsqp, kgam, alph);
  hipLaunchKernelGGL(ds_k2, dim3(1024), dim3(256), 0, stream,
                     dpre, xsqp, upad, wsqp, kgam, alph, (float*)d_out);
}